// Round 5
// baseline (386.927 us; speedup 1.0000x reference)
//
#include <hip/hip_runtime.h>

// Mamba selective scan, fp32. u,delta,z:(4,2048,2048) A:(2048,16)
// B,C:(4,16,2048) D:(2048,). Output y:(4,2048,2048).
// 3-pass chunked scan (chunk op = (S=sum dt, q=local scan)); NC=16 chunks
// of LC=128, staged in 4 subtiles of 32 t (128B = full line per row).
// R9: zero-instruction staging + zero barriers.
//  - global_load_lds (16B/lane) stages u/delta: per-lane PRE-SWIZZLED global
//    source (quarter q = p ^ (row&7), same 128B line -> coalescing intact),
//    linear wave-uniform LDS dest, XOR on the read side (rule #21 both-sides).
//    2 lanes/bank on every LDS access = free. No staging VGPRs, no ds_writes.
//  - B/C pre-transposed once to Bt/Ct[b][t][16] (1MB, tiny kernel): inner
//    loop reads them as wave-uniform 64B loads (1 request/inst, L1-resident).
//    Kills Bc/Cc LDS + its staging + the last __syncthreads.
//  - Wave-private LDS rows, no barriers anywhere; per subtile: vmcnt(0),
//    compute, drain, issue DMA(st+1). ~800cy stall / ~6000cy subtile,
//    covered by 4 waves/SIMD (2 blocks/CU, LDS 64KB, VGPR capped 128).
//  - R8 lesson kept: never split a 128B line across subtiles (L2 can't hold
//    it: co-resident blocks stream ~15MB/XCD in the gap).

#define BATCHSZ 4
#define DIN 2048
#define NSTATE 16
#define SEQ 2048
#define NCH (BATCHSZ * DIN)     // 8192 channels
#define NGRP (NCH / 256)        // 32 channel-groups of 256
#define NC 16                   // chunks per channel
#define LC (SEQ / NC)           // 128 t per chunk
#define SUB 32                  // t per stage tile = 128 B per row
#define NSUB (LC / SUB)         // 4
#define L2E 1.44269504f

__device__ __forceinline__ float softplus_f(float v) {
    float e = __builtin_amdgcn_exp2f(v * L2E);
    return 0.69314718f * __builtin_amdgcn_logf(1.0f + e);
}

__device__ __forceinline__ float silu_f(float v) {
    float s = __builtin_amdgcn_rcpf(1.0f + __builtin_amdgcn_exp2f(-v * L2E));
    return v * s;
}

__device__ __forceinline__ float comp4(const float4& f, int k) {
    return k == 0 ? f.x : k == 1 ? f.y : k == 2 ? f.z : f.w;
}

__device__ __forceinline__ void set4(float4& f, int k, float v) {
    if (k == 0) f.x = v; else if (k == 1) f.y = v; else if (k == 2) f.z = v; else f.w = v;
}

__device__ __forceinline__ void dma16(const float* g, float* l) {
    __builtin_amdgcn_global_load_lds(
        (const __attribute__((address_space(1))) void*)g,
        (__attribute__((address_space(3))) void*)l, 16, 0, 0);
}

// ws layout: wsq[(n*NC+c)*NCH+bd] | wsS[c*NCH+bd] | Bt[b][t][n] | Ct[b][t][n]

// Pre-transpose B,C to [b][t][16] so the scan reads them wave-uniform.
__global__ __launch_bounds__(256) void k_transBC(
        const float* __restrict__ Bm, const float* __restrict__ Cm,
        float* __restrict__ Bt, float* __restrict__ Ct) {
    int idx = blockIdx.x * 256 + threadIdx.x;   // 0 .. 4*2048-1
    int b = idx >> 11;
    int t = idx & (SEQ - 1);
    const float* sb = Bm + (size_t)b * NSTATE * SEQ + t;
    const float* sc = Cm + (size_t)b * NSTATE * SEQ + t;
    float* db = Bt + ((size_t)b * SEQ + t) * NSTATE;
    float* dc = Ct + ((size_t)b * SEQ + t) * NSTATE;
    #pragma unroll
    for (int m = 0; m < 4; ++m) {
        float4 v, w;
        v.x = sb[(size_t)(m * 4 + 0) * SEQ]; w.x = sc[(size_t)(m * 4 + 0) * SEQ];
        v.y = sb[(size_t)(m * 4 + 1) * SEQ]; w.y = sc[(size_t)(m * 4 + 1) * SEQ];
        v.z = sb[(size_t)(m * 4 + 2) * SEQ]; w.z = sc[(size_t)(m * 4 + 2) * SEQ];
        v.w = sb[(size_t)(m * 4 + 3) * SEQ]; w.w = sc[(size_t)(m * 4 + 3) * SEQ];
        *(float4*)(db + m * 4) = v;
        *(float4*)(dc + m * 4) = w;
    }
}

// Pass 1: per (256-channel group, chunk) local scan from zero -> (q[16], S).
__global__ __launch_bounds__(256, 4) void k_pass1(
        const float* __restrict__ u, const float* __restrict__ delta,
        const float* __restrict__ A, const float* __restrict__ Bt,
        float* __restrict__ wsq, float* __restrict__ wsS) {
    __shared__ float Ub[256 * 32];
    __shared__ float Db[256 * 32];

    int tid = threadIdx.x;
    int l = tid & 63;
    int w6 = tid & ~63;
    int g = blockIdx.x & (NGRP - 1);
    int c = blockIdx.x >> 5;               // wave-uniform
    int chBase = g << 8;
    int b = chBase >> 11;
    int bd = chBase + tid;
    int d = bd & (DIN - 1);
    int rowA = w6 + (l >> 3);              // this lane's staging row (+8*it)
    int lq = l & 7;                        // physical 16B quarter

    const float* ug = u + (size_t)chBase * SEQ + (size_t)c * LC;
    const float* dg = delta + (size_t)chBase * SEQ + (size_t)c * LC;
    const float* Btc = Bt + ((size_t)b * SEQ + (size_t)c * LC) * NSTATE;

    float A2[NSTATE];
    {
        const float* Ar = A + (size_t)d * NSTATE;
        #pragma unroll
        for (int n = 0; n < NSTATE; ++n) A2[n] = Ar[n] * L2E;
    }
    float x[NSTATE];
    #pragma unroll
    for (int n = 0; n < NSTATE; ++n) x[n] = 0.0f;
    float S = 0.0f;

    // prologue: stage subtile 0 (8 rows x full 128B line per inst, swizzled src)
    #pragma unroll
    for (int it = 0; it < 8; ++it) {
        int r = rowA + it * 8;
        int q = lq ^ (r & 7);
        dma16(ug + (size_t)r * SEQ + q * 4, &Ub[(w6 + it * 8) * 32]);
        dma16(dg + (size_t)r * SEQ + q * 4, &Db[(w6 + it * 8) * 32]);
    }

    for (int st = 0; st < NSUB; ++st) {
        asm volatile("s_waitcnt vmcnt(0)" ::: "memory");
        __builtin_amdgcn_sched_barrier(0);
        #pragma unroll
        for (int t4 = 0; t4 < 8; ++t4) {
            int ph = (t4 ^ (tid & 7)) * 4;
            float4 u4 = *(const float4*)(&Ub[tid * 32 + ph]);
            float4 d4 = *(const float4*)(&Db[tid * 32 + ph]);
            const float4* Br = (const float4*)(Btc + (size_t)(st * SUB + t4 * 4) * NSTATE);
            #pragma unroll
            for (int k = 0; k < 4; ++k) {
                float dt = softplus_f(comp4(d4, k));
                S += dt;
                float du = dt * comp4(u4, k);
                float bb[NSTATE];
                *(float4*)&bb[0] = Br[k * 4 + 0]; *(float4*)&bb[4] = Br[k * 4 + 1];
                *(float4*)&bb[8] = Br[k * 4 + 2]; *(float4*)&bb[12] = Br[k * 4 + 3];
                #pragma unroll
                for (int n = 0; n < NSTATE; ++n) {
                    float dA = __builtin_amdgcn_exp2f(A2[n] * dt);
                    x[n] = x[n] * dA + du * bb[n];
                }
            }
        }
        if (st + 1 < NSUB) {
            __builtin_amdgcn_sched_barrier(0);
            int tb = (st + 1) * SUB;
            #pragma unroll
            for (int it = 0; it < 8; ++it) {
                int r = rowA + it * 8;
                int q = lq ^ (r & 7);
                dma16(ug + (size_t)r * SEQ + tb + q * 4, &Ub[(w6 + it * 8) * 32]);
                dma16(dg + (size_t)r * SEQ + tb + q * 4, &Db[(w6 + it * 8) * 32]);
            }
        }
    }

    #pragma unroll
    for (int n = 0; n < NSTATE; ++n) wsq[((size_t)n * NC + c) * NCH + bd] = x[n];
    wsS[(size_t)c * NCH + bd] = S;
}

// Pass 2: combine chunk operators, parallel over (n, bd); batch-4 loads.
__global__ __launch_bounds__(256) void k_pass2(
        const float* __restrict__ A, float* __restrict__ wsq,
        float* __restrict__ wsS) {
    int idx = blockIdx.x * 256 + threadIdx.x;   // 0 .. 16*8192-1
    int n = idx >> 13;
    int bd = idx & (NCH - 1);
    int d = bd & (DIN - 1);

    float A2 = A[(size_t)d * NSTATE + n] * L2E;
    float x = 0.0f;
    float* qbase = wsq + (size_t)n * NC * NCH + bd;

    #pragma unroll
    for (int c0 = 0; c0 < NC; c0 += 4) {
        float S0 = wsS[(size_t)(c0 + 0) * NCH + bd];
        float S1 = wsS[(size_t)(c0 + 1) * NCH + bd];
        float S2 = wsS[(size_t)(c0 + 2) * NCH + bd];
        float S3 = wsS[(size_t)(c0 + 3) * NCH + bd];
        float* p0 = qbase + (size_t)(c0 + 0) * NCH;
        float* p1 = qbase + (size_t)(c0 + 1) * NCH;
        float* p2 = qbase + (size_t)(c0 + 2) * NCH;
        float* p3 = qbase + (size_t)(c0 + 3) * NCH;
        float q0 = *p0, q1 = *p1, q2 = *p2, q3 = *p3;
        float t0 = x; x = x * __builtin_amdgcn_exp2f(A2 * S0) + q0;
        float t1 = x; x = x * __builtin_amdgcn_exp2f(A2 * S1) + q1;
        float t2 = x; x = x * __builtin_amdgcn_exp2f(A2 * S2) + q2;
        float t3 = x; x = x * __builtin_amdgcn_exp2f(A2 * S3) + q3;
        *p0 = t0; *p1 = t1; *p2 = t2; *p3 = t3;
    }
}

// Pass 3: rescan from chunk-initial state; emit gated y.
__global__ __launch_bounds__(256, 4) void k_pass3(
        const float* __restrict__ u, const float* __restrict__ delta,
        const float* __restrict__ A, const float* __restrict__ Bt,
        const float* __restrict__ Ct, const float* __restrict__ Dv,
        const float* __restrict__ z, const float* __restrict__ wsq,
        float* __restrict__ out) {
    __shared__ float Ub[256 * 32];          // u in compute, y for drain
    __shared__ float Db[256 * 32];

    int tid = threadIdx.x;
    int l = tid & 63;
    int w6 = tid & ~63;
    int g = blockIdx.x & (NGRP - 1);
    int c = blockIdx.x >> 5;
    int chBase = g << 8;
    int b = chBase >> 11;
    int bd = chBase + tid;
    int d = bd & (DIN - 1);
    int rowA = w6 + (l >> 3);
    int lq = l & 7;

    const float* ug = u + (size_t)chBase * SEQ + (size_t)c * LC;
    const float* dg = delta + (size_t)chBase * SEQ + (size_t)c * LC;
    const float* zg = z + (size_t)chBase * SEQ + (size_t)c * LC;
    float* og = out + (size_t)chBase * SEQ + (size_t)c * LC;
    const float* Btc = Bt + ((size_t)b * SEQ + (size_t)c * LC) * NSTATE;
    const float* Ctc = Ct + ((size_t)b * SEQ + (size_t)c * LC) * NSTATE;

    float A2[NSTATE];
    {
        const float* Ar = A + (size_t)d * NSTATE;
        #pragma unroll
        for (int n = 0; n < NSTATE; ++n) A2[n] = Ar[n] * L2E;
    }
    float x[NSTATE];
    #pragma unroll
    for (int n = 0; n < NSTATE; ++n)
        x[n] = wsq[((size_t)n * NC + c) * NCH + bd];
    float Dd = Dv[d];

    #pragma unroll
    for (int it = 0; it < 8; ++it) {        // prologue stage, subtile 0
        int r = rowA + it * 8;
        int q = lq ^ (r & 7);
        dma16(ug + (size_t)r * SEQ + q * 4, &Ub[(w6 + it * 8) * 32]);
        dma16(dg + (size_t)r * SEQ + q * 4, &Db[(w6 + it * 8) * 32]);
    }

    for (int st = 0; st < NSUB; ++st) {
        int tb = st * SUB;
        asm volatile("s_waitcnt vmcnt(0)" ::: "memory");
        __builtin_amdgcn_sched_barrier(0);
        #pragma unroll
        for (int t4 = 0; t4 < 8; ++t4) {
            int ph = (t4 ^ (tid & 7)) * 4;
            float4 u4 = *(const float4*)(&Ub[tid * 32 + ph]);
            float4 d4 = *(const float4*)(&Db[tid * 32 + ph]);
            const float4* Br = (const float4*)(Btc + (size_t)(tb + t4 * 4) * NSTATE);
            const float4* Cr = (const float4*)(Ctc + (size_t)(tb + t4 * 4) * NSTATE);
            float4 y4;
            #pragma unroll
            for (int k = 0; k < 4; ++k) {
                float uv = comp4(u4, k);
                float dt = softplus_f(comp4(d4, k));
                float du = dt * uv;
                float bb[NSTATE], cc[NSTATE];
                *(float4*)&bb[0] = Br[k * 4 + 0]; *(float4*)&bb[4] = Br[k * 4 + 1];
                *(float4*)&bb[8] = Br[k * 4 + 2]; *(float4*)&bb[12] = Br[k * 4 + 3];
                *(float4*)&cc[0] = Cr[k * 4 + 0]; *(float4*)&cc[4] = Cr[k * 4 + 1];
                *(float4*)&cc[8] = Cr[k * 4 + 2]; *(float4*)&cc[12] = Cr[k * 4 + 3];
                float acc = 0.0f;
                #pragma unroll
                for (int n = 0; n < NSTATE; ++n) {
                    float dA = __builtin_amdgcn_exp2f(A2[n] * dt);
                    x[n] = x[n] * dA + du * bb[n];
                    acc += x[n] * cc[n];
                }
                set4(y4, k, acc + Dd * uv);
            }
            // y back into the exact swizzled slot just consumed
            *(float4*)(&Ub[tid * 32 + ph]) = y4;
        }
        // drain: same-wave rows; read y (swizzled), z direct, gated store
        #pragma unroll
        for (int it = 0; it < 8; ++it) {
            int r = rowA + it * 8;
            int sq = (lq ^ (r & 7)) * 4;
            float4 y4 = *(const float4*)(&Ub[r * 32 + sq]);
            float4 z4 = *(const float4*)(zg + (size_t)r * SEQ + tb + lq * 4);
            float4 oo;
            #pragma unroll
            for (int k = 0; k < 4; ++k)
                set4(oo, k, comp4(y4, k) * silu_f(comp4(z4, k)));
            *(float4*)(og + (size_t)r * SEQ + tb + lq * 4) = oo;
        }
        if (st + 1 < NSUB) {
            __builtin_amdgcn_sched_barrier(0);
            int tb2 = tb + SUB;
            #pragma unroll
            for (int it = 0; it < 8; ++it) {
                int r = rowA + it * 8;
                int q = lq ^ (r & 7);
                dma16(ug + (size_t)r * SEQ + tb2 + q * 4, &Ub[(w6 + it * 8) * 32]);
                dma16(dg + (size_t)r * SEQ + tb2 + q * 4, &Db[(w6 + it * 8) * 32]);
            }
        }
    }
}

// Fallback if ws is too small: one thread per (b,d), full sequential scan.
__global__ __launch_bounds__(256) void k_simple(
        const float* __restrict__ u, const float* __restrict__ delta,
        const float* __restrict__ A, const float* __restrict__ Bm,
        const float* __restrict__ Cm, const float* __restrict__ Dv,
        const float* __restrict__ z, float* __restrict__ out) {
    int bd = blockIdx.x * 256 + threadIdx.x;
    int b  = bd >> 11;
    int d  = bd & (DIN - 1);

    float A2[NSTATE];
    const float* Ar = A + d * NSTATE;
    #pragma unroll
    for (int n = 0; n < NSTATE; ++n) A2[n] = Ar[n] * L2E;
    float x[NSTATE];
    #pragma unroll
    for (int n = 0; n < NSTATE; ++n) x[n] = 0.0f;

    float Dd = Dv[d];
    size_t base = (size_t)bd * SEQ;
    const float4* u4 = (const float4*)(u + base);
    const float4* d4 = (const float4*)(delta + base);
    const float4* z4 = (const float4*)(z + base);
    float4* o4 = (float4*)(out + base);
    const float* Bp = Bm + (size_t)b * NSTATE * SEQ;
    const float* Cp = Cm + (size_t)b * NSTATE * SEQ;

    for (int t4 = 0; t4 < SEQ / 4; ++t4) {
        float4 uu = u4[t4];
        float4 dd = d4[t4];
        float4 zz = z4[t4];
        float4 yy;
        #pragma unroll
        for (int k = 0; k < 4; ++k) {
            float uvk = comp4(uu, k);
            float dt = softplus_f(comp4(dd, k));
            float du = dt * uvk;
            int t = t4 * 4 + k;
            float acc = 0.0f;
            #pragma unroll
            for (int n = 0; n < NSTATE; ++n) {
                float dA = __builtin_amdgcn_exp2f(A2[n] * dt);
                x[n] = x[n] * dA + du * Bp[n * SEQ + t];
                acc += x[n] * Cp[n * SEQ + t];
            }
            float y = acc + Dd * uvk;
            y = y * silu_f(comp4(zz, k));
            set4(yy, k, y);
        }
        o4[t4] = yy;
    }
}

extern "C" void kernel_launch(void* const* d_in, const int* in_sizes, int n_in,
                              void* d_out, int out_size, void* d_ws, size_t ws_size,
                              hipStream_t stream) {
    const float* u     = (const float*)d_in[0];
    const float* delta = (const float*)d_in[1];
    const float* A     = (const float*)d_in[2];
    const float* Bm    = (const float*)d_in[3];
    const float* Cm    = (const float*)d_in[4];
    const float* Dv    = (const float*)d_in[5];
    const float* z     = (const float*)d_in[6];
    float* out = (float*)d_out;
    float* ws = (float*)d_ws;

    size_t nq = (size_t)NSTATE * NC * NCH;          // wsq floats
    size_t ns = (size_t)NC * NCH;                   // wsS floats
    size_t nt = (size_t)BATCHSZ * SEQ * NSTATE;     // Bt floats (Ct same)
    size_t need = (nq + ns + 2 * nt) * sizeof(float);   // ~10 MB

    if (ws_size >= need) {
        float* wsq = ws;
        float* wsS = wsq + nq;
        float* Bt  = wsS + ns;
        float* Ct  = Bt + nt;
        k_transBC<<<(BATCHSZ * SEQ) / 256, 256, 0, stream>>>(Bm, Cm, Bt, Ct);
        k_pass1<<<NGRP * NC, 256, 0, stream>>>(u, delta, A, Bt, wsq, wsS);
        k_pass2<<<(NSTATE * NCH) / 256, 256, 0, stream>>>(A, wsq, wsS);
        k_pass3<<<NGRP * NC, 256, 0, stream>>>(u, delta, A, Bt, Ct, Dv, z, wsq, out);
    } else {
        k_simple<<<NCH / 256, 256, 0, stream>>>(u, delta, A, Bm, Cm, Dv, z, out);
    }
}

// Round 6
// 378.400 us; speedup vs baseline: 1.0225x; 1.0225x over previous
//
#include <hip/hip_runtime.h>

// Mamba selective scan, fp32. u,delta,z:(4,2048,2048) A:(2048,16)
// B,C:(4,16,2048) D:(2048,). Output y:(4,2048,2048).
// 3-pass chunked scan (chunk op = (S=sum dt, q=local scan)); NC=16 chunks
// of LC=128, staged in 4 subtiles of 32 t (128B = full line per row).
// R10: T14 register staging (issue-early / write-late). R9's global_load_lds
// forced "issue DMA -> vmcnt(0) -> compute": the LDS dest is live until the
// drain, so prefetch couldn't be issued early, and at 2 blocks/CU (64KB LDS)
// the exposed DMA round-trip per subtile dominated (VALUBusy 39%, occ 10%,
// traffic clean). Now per subtile:
//   ds_write regs->LDS | issue u/d(st+1) loads->regs | compute | drain |
//   issue z(st+1)->regs
// Prefetched data rides in VGPRs for a full compute+drain (~4000cy) before
// use -> zero steady-state stall, single-buffered LDS, ZERO barriers
// (wave-private rows). Swizzle: write quarter lq^(r&7), compute reads
// t4^(tid&7) -> every LDS op is the 8-phase b128 minimum, conflict-free.
// VGPR is free real estate here (LDS caps 2 waves/SIMD): ~200 VGPR, cap 256
// via __launch_bounds__(256,2). All reg arrays indexed by unrolled `it` only.

#define BATCHSZ 4
#define DIN 2048
#define NSTATE 16
#define SEQ 2048
#define NCH (BATCHSZ * DIN)     // 8192 channels
#define NGRP (NCH / 256)        // 32 channel-groups of 256
#define NC 16                   // chunks per channel
#define LC (SEQ / NC)           // 128 t per chunk
#define SUB 32                  // t per stage tile = 128 B per row
#define NSUB (LC / SUB)         // 4
#define L2E 1.44269504f

__device__ __forceinline__ float softplus_f(float v) {
    float e = __builtin_amdgcn_exp2f(v * L2E);
    return 0.69314718f * __builtin_amdgcn_logf(1.0f + e);
}

__device__ __forceinline__ float silu_f(float v) {
    float s = __builtin_amdgcn_rcpf(1.0f + __builtin_amdgcn_exp2f(-v * L2E));
    return v * s;
}

__device__ __forceinline__ float comp4(const float4& f, int k) {
    return k == 0 ? f.x : k == 1 ? f.y : k == 2 ? f.z : f.w;
}

__device__ __forceinline__ void set4(float4& f, int k, float v) {
    if (k == 0) f.x = v; else if (k == 1) f.y = v; else if (k == 2) f.z = v; else f.w = v;
}

// ws layout: wsq[(n*NC+c)*NCH+bd] | wsS[c*NCH+bd] | Bt[b][t][n] | Ct[b][t][n]

// Pre-transpose B,C to [b][t][16] so the scan reads them wave-uniform.
__global__ __launch_bounds__(256) void k_transBC(
        const float* __restrict__ Bm, const float* __restrict__ Cm,
        float* __restrict__ Bt, float* __restrict__ Ct) {
    int idx = blockIdx.x * 256 + threadIdx.x;   // 0 .. 4*2048-1
    int b = idx >> 11;
    int t = idx & (SEQ - 1);
    const float* sb = Bm + (size_t)b * NSTATE * SEQ + t;
    const float* sc = Cm + (size_t)b * NSTATE * SEQ + t;
    float* db = Bt + ((size_t)b * SEQ + t) * NSTATE;
    float* dc = Ct + ((size_t)b * SEQ + t) * NSTATE;
    #pragma unroll
    for (int m = 0; m < 4; ++m) {
        float4 v, w;
        v.x = sb[(size_t)(m * 4 + 0) * SEQ]; w.x = sc[(size_t)(m * 4 + 0) * SEQ];
        v.y = sb[(size_t)(m * 4 + 1) * SEQ]; w.y = sc[(size_t)(m * 4 + 1) * SEQ];
        v.z = sb[(size_t)(m * 4 + 2) * SEQ]; w.z = sc[(size_t)(m * 4 + 2) * SEQ];
        v.w = sb[(size_t)(m * 4 + 3) * SEQ]; w.w = sc[(size_t)(m * 4 + 3) * SEQ];
        *(float4*)(db + m * 4) = v;
        *(float4*)(dc + m * 4) = w;
    }
}

// Pass 1: per (256-channel group, chunk) local scan from zero -> (q[16], S).
__global__ __launch_bounds__(256, 2) void k_pass1(
        const float* __restrict__ u, const float* __restrict__ delta,
        const float* __restrict__ A, const float* __restrict__ Bt,
        float* __restrict__ wsq, float* __restrict__ wsS) {
    __shared__ float Ub[256 * 32];
    __shared__ float Db[256 * 32];

    int tid = threadIdx.x;
    int l = tid & 63;
    int w6 = tid & ~63;
    int g = blockIdx.x & (NGRP - 1);
    int c = blockIdx.x >> 5;               // wave-uniform
    int chBase = g << 8;
    int b = chBase >> 11;
    int bd = chBase + tid;
    int d = bd & (DIN - 1);
    int rowA = w6 + (l >> 3);              // staging row for it=0 (+8 per it)
    int lq = l & 7;                        // this lane's 16B quarter

    const float* ug = u + (size_t)chBase * SEQ + (size_t)c * LC;
    const float* dg = delta + (size_t)chBase * SEQ + (size_t)c * LC;
    const float* Btc = Bt + ((size_t)b * SEQ + (size_t)c * LC) * NSTATE;

    float A2[NSTATE];
    {
        const float* Ar = A + (size_t)d * NSTATE;
        #pragma unroll
        for (int n = 0; n < NSTATE; ++n) A2[n] = Ar[n] * L2E;
    }
    float x[NSTATE];
    #pragma unroll
    for (int n = 0; n < NSTATE; ++n) x[n] = 0.0f;
    float S = 0.0f;

    // Prologue: subtile-0 loads to registers (8 full 128B lines per inst).
    float4 ur[8], dr[8];
    #pragma unroll
    for (int it = 0; it < 8; ++it) {
        int r = rowA + it * 8;
        ur[it] = *(const float4*)(ug + (size_t)r * SEQ + lq * 4);
        dr[it] = *(const float4*)(dg + (size_t)r * SEQ + lq * 4);
    }

    for (int st = 0; st < NSUB; ++st) {
        int tb = st * SUB;
        // 1. write-late: regs -> LDS, swizzled quarter (8-phase min, no conflict)
        #pragma unroll
        for (int it = 0; it < 8; ++it) {
            int r = rowA + it * 8;
            int p = lq ^ (r & 7);
            *(float4*)(&Ub[r * 32 + p * 4]) = ur[it];
            *(float4*)(&Db[r * 32 + p * 4]) = dr[it];
        }
        // 2. issue-early: next subtile's loads (ride in VGPRs through compute)
        if (st + 1 < NSUB) {
            #pragma unroll
            for (int it = 0; it < 8; ++it) {
                int r = rowA + it * 8;
                ur[it] = *(const float4*)(ug + (size_t)r * SEQ + tb + SUB + lq * 4);
                dr[it] = *(const float4*)(dg + (size_t)r * SEQ + tb + SUB + lq * 4);
            }
        }
        // 3. compute (wave-private rows; compiler orders ds_write->ds_read)
        #pragma unroll
        for (int t4 = 0; t4 < 8; ++t4) {
            int ph = (t4 ^ (tid & 7)) * 4;
            float4 u4 = *(const float4*)(&Ub[tid * 32 + ph]);
            float4 d4 = *(const float4*)(&Db[tid * 32 + ph]);
            const float4* Br = (const float4*)(Btc + (size_t)(tb + t4 * 4) * NSTATE);
            #pragma unroll
            for (int k = 0; k < 4; ++k) {
                float dt = softplus_f(comp4(d4, k));
                S += dt;
                float du = dt * comp4(u4, k);
                float bb[NSTATE];
                *(float4*)&bb[0] = Br[k * 4 + 0]; *(float4*)&bb[4] = Br[k * 4 + 1];
                *(float4*)&bb[8] = Br[k * 4 + 2]; *(float4*)&bb[12] = Br[k * 4 + 3];
                #pragma unroll
                for (int n = 0; n < NSTATE; ++n) {
                    float dA = __builtin_amdgcn_exp2f(A2[n] * dt);
                    x[n] = x[n] * dA + du * bb[n];
                }
            }
        }
    }

    #pragma unroll
    for (int n = 0; n < NSTATE; ++n) wsq[((size_t)n * NC + c) * NCH + bd] = x[n];
    wsS[(size_t)c * NCH + bd] = S;
}

// Pass 2: combine chunk operators, parallel over (n, bd); batch-4 loads.
__global__ __launch_bounds__(256) void k_pass2(
        const float* __restrict__ A, float* __restrict__ wsq,
        float* __restrict__ wsS) {
    int idx = blockIdx.x * 256 + threadIdx.x;   // 0 .. 16*8192-1
    int n = idx >> 13;
    int bd = idx & (NCH - 1);
    int d = bd & (DIN - 1);

    float A2 = A[(size_t)d * NSTATE + n] * L2E;
    float x = 0.0f;
    float* qbase = wsq + (size_t)n * NC * NCH + bd;

    #pragma unroll
    for (int c0 = 0; c0 < NC; c0 += 4) {
        float S0 = wsS[(size_t)(c0 + 0) * NCH + bd];
        float S1 = wsS[(size_t)(c0 + 1) * NCH + bd];
        float S2 = wsS[(size_t)(c0 + 2) * NCH + bd];
        float S3 = wsS[(size_t)(c0 + 3) * NCH + bd];
        float* p0 = qbase + (size_t)(c0 + 0) * NCH;
        float* p1 = qbase + (size_t)(c0 + 1) * NCH;
        float* p2 = qbase + (size_t)(c0 + 2) * NCH;
        float* p3 = qbase + (size_t)(c0 + 3) * NCH;
        float q0 = *p0, q1 = *p1, q2 = *p2, q3 = *p3;
        float t0 = x; x = x * __builtin_amdgcn_exp2f(A2 * S0) + q0;
        float t1 = x; x = x * __builtin_amdgcn_exp2f(A2 * S1) + q1;
        float t2 = x; x = x * __builtin_amdgcn_exp2f(A2 * S2) + q2;
        float t3 = x; x = x * __builtin_amdgcn_exp2f(A2 * S3) + q3;
        *p0 = t0; *p1 = t1; *p2 = t2; *p3 = t3;
    }
}

// Pass 3: rescan from chunk-initial state; emit gated y.
__global__ __launch_bounds__(256, 2) void k_pass3(
        const float* __restrict__ u, const float* __restrict__ delta,
        const float* __restrict__ A, const float* __restrict__ Bt,
        const float* __restrict__ Ct, const float* __restrict__ Dv,
        const float* __restrict__ z, const float* __restrict__ wsq,
        float* __restrict__ out) {
    __shared__ float Ub[256 * 32];          // u in compute, y for drain
    __shared__ float Db[256 * 32];

    int tid = threadIdx.x;
    int l = tid & 63;
    int w6 = tid & ~63;
    int g = blockIdx.x & (NGRP - 1);
    int c = blockIdx.x >> 5;
    int chBase = g << 8;
    int b = chBase >> 11;
    int bd = chBase + tid;
    int d = bd & (DIN - 1);
    int rowA = w6 + (l >> 3);
    int lq = l & 7;

    const float* ug = u + (size_t)chBase * SEQ + (size_t)c * LC;
    const float* dg = delta + (size_t)chBase * SEQ + (size_t)c * LC;
    const float* zg = z + (size_t)chBase * SEQ + (size_t)c * LC;
    float* og = out + (size_t)chBase * SEQ + (size_t)c * LC;
    const float* Btc = Bt + ((size_t)b * SEQ + (size_t)c * LC) * NSTATE;
    const float* Ctc = Ct + ((size_t)b * SEQ + (size_t)c * LC) * NSTATE;

    float A2[NSTATE];
    {
        const float* Ar = A + (size_t)d * NSTATE;
        #pragma unroll
        for (int n = 0; n < NSTATE; ++n) A2[n] = Ar[n] * L2E;
    }
    float x[NSTATE];
    #pragma unroll
    for (int n = 0; n < NSTATE; ++n)
        x[n] = wsq[((size_t)n * NC + c) * NCH + bd];
    float Dd = Dv[d];

    // Prologue: subtile-0 u/delta/z loads to registers.
    float4 ur[8], dr[8], zr[8];
    #pragma unroll
    for (int it = 0; it < 8; ++it) {
        int r = rowA + it * 8;
        ur[it] = *(const float4*)(ug + (size_t)r * SEQ + lq * 4);
        dr[it] = *(const float4*)(dg + (size_t)r * SEQ + lq * 4);
        zr[it] = *(const float4*)(zg + (size_t)r * SEQ + lq * 4);
    }

    for (int st = 0; st < NSUB; ++st) {
        int tb = st * SUB;
        // 1. write-late: regs -> LDS (swizzled quarter)
        #pragma unroll
        for (int it = 0; it < 8; ++it) {
            int r = rowA + it * 8;
            int p = lq ^ (r & 7);
            *(float4*)(&Ub[r * 32 + p * 4]) = ur[it];
            *(float4*)(&Db[r * 32 + p * 4]) = dr[it];
        }
        // 2. issue-early: next u/delta (WAR-safe: step 1 consumed the regs)
        if (st + 1 < NSUB) {
            #pragma unroll
            for (int it = 0; it < 8; ++it) {
                int r = rowA + it * 8;
                ur[it] = *(const float4*)(ug + (size_t)r * SEQ + tb + SUB + lq * 4);
                dr[it] = *(const float4*)(dg + (size_t)r * SEQ + tb + SUB + lq * 4);
            }
        }
        // 3. compute; y overwrites the exact u-slot consumed
        #pragma unroll
        for (int t4 = 0; t4 < 8; ++t4) {
            int ph = (t4 ^ (tid & 7)) * 4;
            float4 u4 = *(const float4*)(&Ub[tid * 32 + ph]);
            float4 d4 = *(const float4*)(&Db[tid * 32 + ph]);
            const float4* Br = (const float4*)(Btc + (size_t)(tb + t4 * 4) * NSTATE);
            const float4* Cr = (const float4*)(Ctc + (size_t)(tb + t4 * 4) * NSTATE);
            float4 y4;
            #pragma unroll
            for (int k = 0; k < 4; ++k) {
                float uv = comp4(u4, k);
                float dt = softplus_f(comp4(d4, k));
                float du = dt * uv;
                float bb[NSTATE], cc[NSTATE];
                *(float4*)&bb[0] = Br[k * 4 + 0]; *(float4*)&bb[4] = Br[k * 4 + 1];
                *(float4*)&bb[8] = Br[k * 4 + 2]; *(float4*)&bb[12] = Br[k * 4 + 3];
                *(float4*)&cc[0] = Cr[k * 4 + 0]; *(float4*)&cc[4] = Cr[k * 4 + 1];
                *(float4*)&cc[8] = Cr[k * 4 + 2]; *(float4*)&cc[12] = Cr[k * 4 + 3];
                float acc = 0.0f;
                #pragma unroll
                for (int n = 0; n < NSTATE; ++n) {
                    float dA = __builtin_amdgcn_exp2f(A2[n] * dt);
                    x[n] = x[n] * dA + du * bb[n];
                    acc += x[n] * cc[n];
                }
                set4(y4, k, acc + Dd * uv);
            }
            *(float4*)(&Ub[tid * 32 + ph]) = y4;
        }
        // 4. drain: y from Ub (swizzled), silu(z regs), coalesced store
        #pragma unroll
        for (int it = 0; it < 8; ++it) {
            int r = rowA + it * 8;
            int p = lq ^ (r & 7);
            float4 y4 = *(const float4*)(&Ub[r * 32 + p * 4]);
            float4 oo;
            #pragma unroll
            for (int k = 0; k < 4; ++k)
                set4(oo, k, comp4(y4, k) * silu_f(comp4(zr[it], k)));
            *(float4*)(og + (size_t)r * SEQ + tb + lq * 4) = oo;
        }
        // 5. issue next z (after drain consumed zr: WAR-safe)
        if (st + 1 < NSUB) {
            #pragma unroll
            for (int it = 0; it < 8; ++it) {
                int r = rowA + it * 8;
                zr[it] = *(const float4*)(zg + (size_t)r * SEQ + tb + SUB + lq * 4);
            }
        }
    }
}

// Fallback if ws is too small: one thread per (b,d), full sequential scan.
__global__ __launch_bounds__(256) void k_simple(
        const float* __restrict__ u, const float* __restrict__ delta,
        const float* __restrict__ A, const float* __restrict__ Bm,
        const float* __restrict__ Cm, const float* __restrict__ Dv,
        const float* __restrict__ z, float* __restrict__ out) {
    int bd = blockIdx.x * 256 + threadIdx.x;
    int b  = bd >> 11;
    int d  = bd & (DIN - 1);

    float A2[NSTATE];
    const float* Ar = A + d * NSTATE;
    #pragma unroll
    for (int n = 0; n < NSTATE; ++n) A2[n] = Ar[n] * L2E;
    float x[NSTATE];
    #pragma unroll
    for (int n = 0; n < NSTATE; ++n) x[n] = 0.0f;

    float Dd = Dv[d];
    size_t base = (size_t)bd * SEQ;
    const float4* u4 = (const float4*)(u + base);
    const float4* d4 = (const float4*)(delta + base);
    const float4* z4 = (const float4*)(z + base);
    float4* o4 = (float4*)(out + base);
    const float* Bp = Bm + (size_t)b * NSTATE * SEQ;
    const float* Cp = Cm + (size_t)b * NSTATE * SEQ;

    for (int t4 = 0; t4 < SEQ / 4; ++t4) {
        float4 uu = u4[t4];
        float4 dd = d4[t4];
        float4 zz = z4[t4];
        float4 yy;
        #pragma unroll
        for (int k = 0; k < 4; ++k) {
            float uvk = comp4(uu, k);
            float dt = softplus_f(comp4(dd, k));
            float du = dt * uvk;
            int t = t4 * 4 + k;
            float acc = 0.0f;
            #pragma unroll
            for (int n = 0; n < NSTATE; ++n) {
                float dA = __builtin_amdgcn_exp2f(A2[n] * dt);
                x[n] = x[n] * dA + du * Bp[n * SEQ + t];
                acc += x[n] * Cp[n * SEQ + t];
            }
            float y = acc + Dd * uvk;
            y = y * silu_f(comp4(zz, k));
            set4(yy, k, y);
        }
        o4[t4] = yy;
    }
}

extern "C" void kernel_launch(void* const* d_in, const int* in_sizes, int n_in,
                              void* d_out, int out_size, void* d_ws, size_t ws_size,
                              hipStream_t stream) {
    const float* u     = (const float*)d_in[0];
    const float* delta = (const float*)d_in[1];
    const float* A     = (const float*)d_in[2];
    const float* Bm    = (const float*)d_in[3];
    const float* Cm    = (const float*)d_in[4];
    const float* Dv    = (const float*)d_in[5];
    const float* z     = (const float*)d_in[6];
    float* out = (float*)d_out;
    float* ws = (float*)d_ws;

    size_t nq = (size_t)NSTATE * NC * NCH;          // wsq floats
    size_t ns = (size_t)NC * NCH;                   // wsS floats
    size_t nt = (size_t)BATCHSZ * SEQ * NSTATE;     // Bt floats (Ct same)
    size_t need = (nq + ns + 2 * nt) * sizeof(float);   // ~10 MB

    if (ws_size >= need) {
        float* wsq = ws;
        float* wsS = wsq + nq;
        float* Bt  = wsS + ns;
        float* Ct  = Bt + nt;
        k_transBC<<<(BATCHSZ * SEQ) / 256, 256, 0, stream>>>(Bm, Cm, Bt, Ct);
        k_pass1<<<NGRP * NC, 256, 0, stream>>>(u, delta, A, Bt, wsq, wsS);
        k_pass2<<<(NSTATE * NCH) / 256, 256, 0, stream>>>(A, wsq, wsS);
        k_pass3<<<NGRP * NC, 256, 0, stream>>>(u, delta, A, Bt, Ct, Dv, z, wsq, out);
    } else {
        k_simple<<<NCH / 256, 256, 0, stream>>>(u, delta, A, Bm, Cm, Dv, z, out);
    }
}